// Round 9
// baseline (126.844 us; speedup 1.0000x reference)
//
#include <hip/hip_runtime.h>

// MapNet forward (R8): slot-gather formulation.
// The pixel->cell map is feature-invariant, and cell occupancy is sparse
// (~3.8K valid pixels into 11904 live cells). Build per-cell fixed slot
// lists ONCE per batch (4 x u16 pixel idx, 0xFFFF = empty, + overflow list),
// then the hot kernel is a pure gather: slot indices in REGISTERS across an
// 8-feature loop, independent predicated L1 loads from the 16KB plane,
// EPS-seeded max (preserves negative maxima), empty->0, coalesced NT f32x4
// stores. No LDS / atomics / barriers in the hot kernel. Valid rows are
// provably [27,119]; rows 0..26 & 120..127 streamed as zeros. Cells with >4
// pixels (rare) patched by a tiny global-atomicMaxF fixup kernel.
//
// bs=64, F=64, h=w=64, H=W=256, K=4, s=128, fx=fy=cx=cy=128, EPS=-1e16

#define S 128
#define EPS_F (-1e16f)
#define LIVE 11904               // 93 live rows * 128
#define CELL0 3456               // 27*128: live region offset in cells
#define CAP_OVF 4096
#define WS_STRIDE 131072         // 128 KB per batch in d_ws (8 MB total)
#define OVF_CNT_OFF 95232        // after slots (11904*4*2B)
#define OVF_OFF 95240

typedef __attribute__((ext_vector_type(4))) float f32x4;

__device__ __forceinline__ void atomicMaxF(float* a, float v) {
    if (v >= 0.0f) atomicMax(reinterpret_cast<int*>(a), __float_as_int(v));
    else atomicMin(reinterpret_cast<unsigned int*>(a), __float_as_uint(v));
}

// ---------------- kernel 1: per-batch slot build ----------------
__global__ __launch_bounds__(1024) void slot_build(
        const float* __restrict__ depth,   // (64,3,256,256)
        unsigned char* __restrict__ ws) {
    __shared__ unsigned int cnt[LIVE];     // 47.6 KB

    const int t = threadIdx.x;
    const int b = blockIdx.x;

    unsigned long long* slots64 =
        reinterpret_cast<unsigned long long*>(ws + (size_t)b * WS_STRIDE);
    unsigned int* ovf_cnt =
        reinterpret_cast<unsigned int*>(ws + (size_t)b * WS_STRIDE + OVF_CNT_OFF);
    unsigned int* ovf =
        reinterpret_cast<unsigned int*>(ws + (size_t)b * WS_STRIDE + OVF_OFF);

    // zero LDS counters; init all slots to empty (0xFFFF); zero overflow count
    for (int i = t; i < LIVE; i += 1024) cnt[i] = 0;
    for (int i = t; i < LIVE; i += 1024) slots64[i] = ~0ull;
    if (t == 0) *ovf_cnt = 0;

    // ---- pixel->cell map, 4 consecutive pixels per thread (exact JAX math) ----
    const float* dp = depth + (size_t)b * 3 * 256 * 256;  // channel-0 plane
    const int p0 = 4 * t;
    const int r = (p0 >> 6) * 4 + 2;
    const int cbase = (p0 & 63) * 4 + 2;
    const float* drow = dp + r * 256 + cbase;
    int cell[4];
    #pragma unroll
    for (int q = 0; q < 4; ++q) {
        float Z = drow[4 * q] * 10.0f;                  // depth -> meters
        int c = cbase + 4 * q;
        bool valid = fabsf(Z) > 0.8f;
        // f32 div by 0.1f, rint (half-even); /128 exact pow2
        float X = (((float)c - 128.0f) * (1.0f / 128.0f)) * Z;
        int zi = (int)rintf(-(Z / 0.1f) + 127.0f);
        int xi = (int)rintf(X / 0.1f + 63.5f);
        int zr = zi - 27;                               // row within live grid
        bool ok = valid & ((unsigned)zr < 93u) & ((unsigned)xi < (unsigned)S);
        cell[q] = ok ? (zr * S + xi) : -1;
    }

    __syncthreads();  // vmcnt(0)+barrier: slot-init stores visible block-wide

    unsigned short* slots16 = reinterpret_cast<unsigned short*>(slots64);
    #pragma unroll
    for (int q = 0; q < 4; ++q) {
        if (cell[q] >= 0) {
            unsigned int pos = atomicAdd(&cnt[cell[q]], 1u);
            if (pos < 4u) {
                slots16[cell[q] * 4 + pos] = (unsigned short)(p0 + q);
            } else {
                unsigned int idx = atomicAdd(ovf_cnt, 1u);
                if (idx < CAP_OVF) ovf[idx] = ((unsigned)cell[q] << 12) | (unsigned)(p0 + q);
            }
        }
    }
}

// ---------------- kernel 2: gather + zero rows + stream ----------------
// grid 1536 = 64 batches x 8 feature-groups x 3 cell-chunks; 1024 threads
__global__ __launch_bounds__(1024, 2) void gather_slots(
        const float* __restrict__ img,     // (64,64,64,64)
        const unsigned char* __restrict__ ws,
        float* __restrict__ out) {         // (64,64,128,128)
    const int t = threadIdx.x;

    // XCD swizzle: all 24 blocks of a batch's slice set share an XCD L2
    const int id = blockIdx.x;
    const int xcd = id & 7;
    const int s = id >> 3;                 // 0..191
    const int b = xcd * 8 + s / 24;
    const int rem = s % 24;
    const int fg = rem / 3;                // feature group (8 features)
    const int chunk = rem % 3;             // cell chunk: 4096/4096/3712 cells

    // load this thread's 4 cells' slots into registers (held across features)
    const int cell0 = chunk * 4096 + 4 * t;             // live-cell index
    const bool act = (chunk < 2) | (t < 928);           // chunk2: 3712 cells
    const unsigned long long* slots64 =
        reinterpret_cast<const unsigned long long*>(ws + (size_t)b * WS_STRIDE);
    unsigned int sl[4][2];
    if (act) {
        #pragma unroll
        for (int c = 0; c < 4; ++c) {
            unsigned long long v = slots64[cell0 + c];
            sl[c][0] = (unsigned int)v;
            sl[c][1] = (unsigned int)(v >> 32);
        }
    }

    // zero-region share: 1120 f32x4 split 374/374/372 across chunks
    const int zb = chunk * 374;
    const int zn = (chunk < 2) ? 374 : 372;
    const f32x4 zero4 = {0.0f, 0.0f, 0.0f, 0.0f};

    for (int k = 0; k < 8; ++k) {
        const int f = fg * 8 + k;
        const float* plane = img + (size_t)(b * 64 + f) * 4096;   // 16 KB
        f32x4* o4 = reinterpret_cast<f32x4*>(out) + (size_t)(b * 64 + f) * 4096;

        if (t < zn) {             // rows 0..26 (idx<864) and 120..127 (>=3840)
            int z = zb + t;
            int idx = (z < 864) ? z : (3840 + (z - 864));
            __builtin_nontemporal_store(zero4, o4 + idx);
        }

        if (act) {
            f32x4 o;
            #pragma unroll
            for (int c = 0; c < 4; ++c) {
                float v = EPS_F;  // seed at EPS: preserves negative maxima
                unsigned int p01 = sl[c][0], p23 = sl[c][1];
                unsigned int px;
                px = p01 & 0xffffu; if (px != 0xffffu) v = fmaxf(v, plane[px]);
                px = p01 >> 16;     if (px != 0xffffu) v = fmaxf(v, plane[px]);
                px = p23 & 0xffffu; if (px != 0xffffu) v = fmaxf(v, plane[px]);
                px = p23 >> 16;     if (px != 0xffffu) v = fmaxf(v, plane[px]);
                o[c] = (v == EPS_F) ? 0.0f : v;         // empty cell -> 0
            }
            // live region starts at f32x4 index 864; cell0/4 = chunk*1024 + t
            __builtin_nontemporal_store(o, o4 + 864 + chunk * 1024 + t);
        }
    }
}

// ---------------- kernel 3: overflow fixup (rare cells with >4 pixels) ----
__global__ __launch_bounds__(64) void ovf_fix(
        const float* __restrict__ img,
        const unsigned char* __restrict__ ws,
        float* __restrict__ out) {
    const int t = threadIdx.x;
    const int b = blockIdx.x;
    unsigned int n = *reinterpret_cast<const unsigned int*>(
        ws + (size_t)b * WS_STRIDE + OVF_CNT_OFF);
    if (n > CAP_OVF) n = CAP_OVF;
    const unsigned int* ovf = reinterpret_cast<const unsigned int*>(
        ws + (size_t)b * WS_STRIDE + OVF_OFF);

    for (unsigned int j = t; j < n * 64u; j += 64u) {
        unsigned int e = j >> 6;
        unsigned int f = j & 63u;
        unsigned int packed = ovf[e];
        unsigned int cell = packed >> 12;
        unsigned int pix = packed & 0xfffu;
        float v = img[(size_t)(b * 64 + f) * 4096 + pix];
        atomicMaxF(out + (size_t)(b * 64 + f) * 16384 + CELL0 + cell, v);
    }
}

extern "C" void kernel_launch(void* const* d_in, const int* in_sizes, int n_in,
                              void* d_out, int out_size, void* d_ws, size_t ws_size,
                              hipStream_t stream) {
    const float* img = (const float*)d_in[0];    // (64,64,64,64)
    const float* depth = (const float*)d_in[1];  // (64,3,256,256)
    float* out = (float*)d_out;                  // (64,64,128,128)
    unsigned char* ws = (unsigned char*)d_ws;    // 8 MB used

    slot_build<<<64, 1024, 0, stream>>>(depth, ws);
    gather_slots<<<1536, 1024, 0, stream>>>(img, ws, out);
    ovf_fix<<<64, 64, 0, stream>>>(img, ws, out);
}

// Round 10
// 59.613 us; speedup vs baseline: 2.1278x; 2.1278x over previous
//
#include <hip/hip_runtime.h>

// MapNet forward (R9): double-buffered pipelined scatter.
// One block per (batch, 8-feature group), 1024 threads, TWO 48KB LDS grids.
// Per iteration m (one lgkm-only barrier each):
//   sweep+store feature m-1 from grid[(m-1)&1]  (reinit to EPS fused)
//   scatter feature m into grid[m&1]            (LDS atomicMax, monotone enc)
// Sweep-stores overlap the next feature's atomics; only ONE barrier/feature
// (R7 had two). Stores are regular (L2 write-back buffers bursts, like the
// 7 TB/s fill kernel) instead of nontemporal.
// Valid pixels have zi in [27,119] => 93 live rows in LDS; rows 0..26 and
// 120..127 stored as zeros directly (full 1120-f32x4 coverage, R7 bug fixed).
//
// bs=64, F=64, h=w=64, H=W=256, K=4, s=128, fx=fy=cx=cy=128, EPS=-1e16

#define S 128
#define EPS_F (-1e16f)
#define GROWS 93                 // live grid rows (map rows 27..119)
#define GPAD 96                  // allocated rows per grid
#define GSZ (GPAD * S)           // 12288 ints = 48 KB per grid
#define NSWEEP 2976              // GROWS*128/4 int4s swept per feature

typedef __attribute__((ext_vector_type(4))) float f32x4;
typedef __attribute__((ext_vector_type(4))) int i32x4;

// monotone float<->int involution: order-preserving under signed int compare
__device__ __forceinline__ int enc(float x) {
    int i = __float_as_int(x);
    return i ^ ((i >> 31) & 0x7fffffff);
}
__device__ __forceinline__ float dec(int k) {
    return __int_as_float(k ^ ((k >> 31) & 0x7fffffff));
}

// barrier ordering LDS ops only (no vmcnt drain -> stores keep streaming)
__device__ __forceinline__ void barrier_lds() {
    asm volatile("s_waitcnt lgkmcnt(0)\n\ts_barrier" ::: "memory");
    __builtin_amdgcn_sched_barrier(0);
}

__global__ __launch_bounds__(1024, 4) void mapnet_pipe(
        const float* __restrict__ img,    // (64,64,64,64)
        const float* __restrict__ depth,  // (64,3,256,256)
        float* __restrict__ out) {        // (64,64,128,128)
    __shared__ int grid[2][GSZ];          // 96 KB -> 1 block/CU

    const int t = threadIdx.x;            // 0..1023

    // swizzle: all 8 feature-groups of a batch land on one XCD (depth reuse)
    const int j = blockIdx.x;             // 0..511
    const int xcd = j & 7;
    const int slot = j >> 3;              // 0..63
    const int b = xcd * 8 + (slot >> 3);  // batch
    const int f0 = (slot & 7) * 8;        // first feature of this block

    // ---- pixel->cell map, computed once (depth-only, feature-independent) ----
    const float* dp = depth + (size_t)b * 3 * 256 * 256;  // channel-0 plane
    const int p0 = 4 * t;                  // first of 4 consecutive pixels
    const int r = (p0 >> 6) * 4 + 2;       // image row (same for all 4)
    const int cbase = (p0 & 63) * 4 + 2;   // image col of pixel p0
    const float* drow = dp + r * 256 + cbase;
    int cell[4];
    #pragma unroll
    for (int q = 0; q < 4; ++q) {
        float Z = drow[4 * q] * 10.0f;                  // depth -> meters
        int c = cbase + 4 * q;
        bool valid = fabsf(Z) > 0.8f;
        // match JAX exactly: f32 div by 0.1f, rint (half-even); /128 exact
        float X = (((float)c - 128.0f) * (1.0f / 128.0f)) * Z;
        int zi = (int)rintf(-(Z / 0.1f) + 127.0f);
        int xi = (int)rintf(X / 0.1f + 63.5f);
        int zr = zi - 27;                               // row within live grid
        bool ok = valid & ((unsigned)zr < GROWS) & ((unsigned)xi < S);
        cell[q] = ok ? (zr * S + xi) : -1;
    }

    // ---- prologue: init BOTH grids to enc(EPS); prefetch feature 0 ----
    const int EPSK = enc(EPS_F);
    i32x4* gall = reinterpret_cast<i32x4*>(&grid[0][0]);
    const i32x4 epsv = {EPSK, EPSK, EPSK, EPSK};
    #pragma unroll
    for (int m = 0; m < 6; ++m) gall[t + m * 1024] = epsv;  // 6144 int4 = 96KB

    const f32x4* imgb = reinterpret_cast<const f32x4*>(img)
                        + (size_t)(b * 64 + f0) * 1024;     // 1024 f32x4 / feature
    f32x4 iv = __builtin_nontemporal_load(imgb + t);        // pixels 4t..4t+3
    barrier_lds();

    f32x4* outb = reinterpret_cast<f32x4*>(out)
                  + (size_t)(b * 64 + f0) * 4096;           // 4096 f32x4 / feature
    const f32x4 zero4 = {0.0f, 0.0f, 0.0f, 0.0f};

    // ---- iter 0: scatter feature 0 (no sweep yet) ----
    {
        float vs[4] = {iv.x, iv.y, iv.z, iv.w};
        #pragma unroll
        for (int q = 0; q < 4; ++q)
            if (cell[q] >= 0) atomicMax(&grid[0][cell[q]], enc(vs[q]));
        iv = __builtin_nontemporal_load(imgb + 1024 + t);   // prefetch f1
    }

    // ---- steady state: one barrier per feature ----
    for (int m = 1; m < 8; ++m) {
        barrier_lds();   // scatter(m-1) visible; sweep(m-2) of grid[m&1] done

        // sweep+store feature m-1 from grid[(m-1)&1], reinit fused
        {
            f32x4* o4 = outb + (size_t)(m - 1) * 4096;
            // zero rows 0..26 (idx<864) and 120..127 (idx>=3840): 1120 f32x4
            {
                int idx = (t < 864) ? t : (3840 + (t - 864));
                o4[idx] = zero4;
                if (t < 96) o4[4000 + t] = zero4;           // z = 1024..1119
            }
            i32x4* gs = reinterpret_cast<i32x4*>(&grid[(m - 1) & 1][0]);
            #pragma unroll
            for (int mm = 0; mm < 3; ++mm) {
                int idx = t + mm * 1024;
                if (idx < NSWEEP) {
                    i32x4 gk = gs[idx];
                    gs[idx] = epsv;                         // reinit
                    f32x4 o;
                    o.x = (gk.x == EPSK) ? 0.0f : dec(gk.x);
                    o.y = (gk.y == EPSK) ? 0.0f : dec(gk.y);
                    o.z = (gk.z == EPSK) ? 0.0f : dec(gk.z);
                    o.w = (gk.w == EPSK) ? 0.0f : dec(gk.w);
                    o4[864 + idx] = o;                      // rows 27..119
                }
            }
        }

        // scatter feature m into grid[m&1] (overlaps sweep's store drain)
        {
            float vs[4] = {iv.x, iv.y, iv.z, iv.w};
            #pragma unroll
            for (int q = 0; q < 4; ++q)
                if (cell[q] >= 0) atomicMax(&grid[m & 1][cell[q]], enc(vs[q]));
        }
        if (m < 7) iv = __builtin_nontemporal_load(imgb + (size_t)(m + 1) * 1024 + t);
    }

    // ---- epilogue: sweep feature 7 from grid[1] ----
    barrier_lds();
    {
        f32x4* o4 = outb + (size_t)7 * 4096;
        {
            int idx = (t < 864) ? t : (3840 + (t - 864));
            o4[idx] = zero4;
            if (t < 96) o4[4000 + t] = zero4;
        }
        i32x4* gs = reinterpret_cast<i32x4*>(&grid[1][0]);
        #pragma unroll
        for (int mm = 0; mm < 3; ++mm) {
            int idx = t + mm * 1024;
            if (idx < NSWEEP) {
                i32x4 gk = gs[idx];
                f32x4 o;
                o.x = (gk.x == EPSK) ? 0.0f : dec(gk.x);
                o.y = (gk.y == EPSK) ? 0.0f : dec(gk.y);
                o.z = (gk.z == EPSK) ? 0.0f : dec(gk.z);
                o.w = (gk.w == EPSK) ? 0.0f : dec(gk.w);
                o4[864 + idx] = o;
            }
        }
    }
}

extern "C" void kernel_launch(void* const* d_in, const int* in_sizes, int n_in,
                              void* d_out, int out_size, void* d_ws, size_t ws_size,
                              hipStream_t stream) {
    const float* img = (const float*)d_in[0];    // (64,64,64,64)
    const float* depth = (const float*)d_in[1];  // (64,3,256,256)
    float* out = (float*)d_out;                  // (64,64,128,128)

    mapnet_pipe<<<512, 1024, 0, stream>>>(img, depth, out);
}

// Round 11
// 55.339 us; speedup vs baseline: 2.2921x; 1.0772x over previous
//
#include <hip/hip_runtime.h>

// MapNet forward (R10 = R9 with 256 persistent blocks x 16 features).
// One block per (batch, 16-feature group), 1024 threads, TWO 48KB LDS grids.
// Single block-round (256 blocks = 1/CU) -> prologue (grid init, cell map,
// first img load) paid once, no inter-round bubble.
// Per iteration m (one lgkm-only barrier each):
//   sweep+store feature m-1 from grid[(m-1)&1]  (reinit to EPS fused)
//   scatter feature m into grid[m&1]            (LDS atomicMax, monotone enc)
// Valid pixels have zi in [27,119] => 93 live rows in LDS; rows 0..26 and
// 120..127 stored as zeros directly.
//
// bs=64, F=64, h=w=64, H=W=256, K=4, s=128, fx=fy=cx=cy=128, EPS=-1e16

#define S 128
#define EPS_F (-1e16f)
#define GROWS 93                 // live grid rows (map rows 27..119)
#define GPAD 96                  // allocated rows per grid
#define GSZ (GPAD * S)           // 12288 ints = 48 KB per grid
#define NSWEEP 2976              // GROWS*128/4 int4s swept per feature
#define NF 16                    // features per block

typedef __attribute__((ext_vector_type(4))) float f32x4;
typedef __attribute__((ext_vector_type(4))) int i32x4;

// monotone float<->int involution: order-preserving under signed int compare
__device__ __forceinline__ int enc(float x) {
    int i = __float_as_int(x);
    return i ^ ((i >> 31) & 0x7fffffff);
}
__device__ __forceinline__ float dec(int k) {
    return __int_as_float(k ^ ((k >> 31) & 0x7fffffff));
}

// barrier ordering LDS ops only (no vmcnt drain -> stores keep streaming)
__device__ __forceinline__ void barrier_lds() {
    asm volatile("s_waitcnt lgkmcnt(0)\n\ts_barrier" ::: "memory");
    __builtin_amdgcn_sched_barrier(0);
}

__global__ __launch_bounds__(1024, 4) void mapnet_pipe(
        const float* __restrict__ img,    // (64,64,64,64)
        const float* __restrict__ depth,  // (64,3,256,256)
        float* __restrict__ out) {        // (64,64,128,128)
    __shared__ int grid[2][GSZ];          // 96 KB -> 1 block/CU

    const int t = threadIdx.x;            // 0..1023

    // swizzle: each batch's 4 blocks share one XCD (depth/L2 reuse);
    // 256 blocks = 8 XCDs x 8 batches x 4 feature-groups
    const int id = blockIdx.x;            // 0..255
    const int xcd = id & 7;
    const int s = id >> 3;                // 0..31
    const int b = xcd * 8 + (s >> 2);     // batch
    const int f0 = (s & 3) * NF;          // first feature of this block

    // ---- pixel->cell map, computed once (depth-only, feature-independent) ----
    const float* dp = depth + (size_t)b * 3 * 256 * 256;  // channel-0 plane
    const int p0 = 4 * t;                  // first of 4 consecutive pixels
    const int r = (p0 >> 6) * 4 + 2;       // image row (same for all 4)
    const int cbase = (p0 & 63) * 4 + 2;   // image col of pixel p0
    const float* drow = dp + r * 256 + cbase;
    int cell[4];
    #pragma unroll
    for (int q = 0; q < 4; ++q) {
        float Z = drow[4 * q] * 10.0f;                  // depth -> meters
        int c = cbase + 4 * q;
        bool valid = fabsf(Z) > 0.8f;
        // match JAX exactly: f32 div by 0.1f, rint (half-even); /128 exact
        float X = (((float)c - 128.0f) * (1.0f / 128.0f)) * Z;
        int zi = (int)rintf(-(Z / 0.1f) + 127.0f);
        int xi = (int)rintf(X / 0.1f + 63.5f);
        int zr = zi - 27;                               // row within live grid
        bool ok = valid & ((unsigned)zr < GROWS) & ((unsigned)xi < S);
        cell[q] = ok ? (zr * S + xi) : -1;
    }

    // ---- prologue: init BOTH grids to enc(EPS); prefetch feature 0 ----
    const int EPSK = enc(EPS_F);
    i32x4* gall = reinterpret_cast<i32x4*>(&grid[0][0]);
    const i32x4 epsv = {EPSK, EPSK, EPSK, EPSK};
    #pragma unroll
    for (int m = 0; m < 6; ++m) gall[t + m * 1024] = epsv;  // 6144 int4 = 96KB

    const f32x4* imgb = reinterpret_cast<const f32x4*>(img)
                        + (size_t)(b * 64 + f0) * 1024;     // 1024 f32x4 / feature
    f32x4 iv = __builtin_nontemporal_load(imgb + t);        // pixels 4t..4t+3
    barrier_lds();

    f32x4* outb = reinterpret_cast<f32x4*>(out)
                  + (size_t)(b * 64 + f0) * 4096;           // 4096 f32x4 / feature
    const f32x4 zero4 = {0.0f, 0.0f, 0.0f, 0.0f};

    // ---- iter 0: scatter feature 0 (no sweep yet) ----
    {
        float vs[4] = {iv.x, iv.y, iv.z, iv.w};
        #pragma unroll
        for (int q = 0; q < 4; ++q)
            if (cell[q] >= 0) atomicMax(&grid[0][cell[q]], enc(vs[q]));
        iv = __builtin_nontemporal_load(imgb + 1024 + t);   // prefetch f1
    }

    // ---- steady state: one barrier per feature ----
    for (int m = 1; m < NF; ++m) {
        barrier_lds();   // scatter(m-1) visible; sweep(m-2) of grid[m&1] done

        // sweep+store feature m-1 from grid[(m-1)&1], reinit fused
        {
            f32x4* o4 = outb + (size_t)(m - 1) * 4096;
            // zero rows 0..26 (idx<864) and 120..127 (idx>=3840): 1120 f32x4
            {
                int idx = (t < 864) ? t : (3840 + (t - 864));
                o4[idx] = zero4;
                if (t < 96) o4[4000 + t] = zero4;           // z = 1024..1119
            }
            i32x4* gs = reinterpret_cast<i32x4*>(&grid[(m - 1) & 1][0]);
            #pragma unroll
            for (int mm = 0; mm < 3; ++mm) {
                int idx = t + mm * 1024;
                if (idx < NSWEEP) {
                    i32x4 gk = gs[idx];
                    gs[idx] = epsv;                         // reinit
                    f32x4 o;
                    o.x = (gk.x == EPSK) ? 0.0f : dec(gk.x);
                    o.y = (gk.y == EPSK) ? 0.0f : dec(gk.y);
                    o.z = (gk.z == EPSK) ? 0.0f : dec(gk.z);
                    o.w = (gk.w == EPSK) ? 0.0f : dec(gk.w);
                    o4[864 + idx] = o;                      // rows 27..119
                }
            }
        }

        // scatter feature m into grid[m&1] (overlaps sweep's store drain)
        {
            float vs[4] = {iv.x, iv.y, iv.z, iv.w};
            #pragma unroll
            for (int q = 0; q < 4; ++q)
                if (cell[q] >= 0) atomicMax(&grid[m & 1][cell[q]], enc(vs[q]));
        }
        if (m < NF - 1)
            iv = __builtin_nontemporal_load(imgb + (size_t)(m + 1) * 1024 + t);
    }

    // ---- epilogue: sweep feature NF-1 from grid[(NF-1)&1] ----
    barrier_lds();
    {
        f32x4* o4 = outb + (size_t)(NF - 1) * 4096;
        {
            int idx = (t < 864) ? t : (3840 + (t - 864));
            o4[idx] = zero4;
            if (t < 96) o4[4000 + t] = zero4;
        }
        i32x4* gs = reinterpret_cast<i32x4*>(&grid[(NF - 1) & 1][0]);
        #pragma unroll
        for (int mm = 0; mm < 3; ++mm) {
            int idx = t + mm * 1024;
            if (idx < NSWEEP) {
                i32x4 gk = gs[idx];
                f32x4 o;
                o.x = (gk.x == EPSK) ? 0.0f : dec(gk.x);
                o.y = (gk.y == EPSK) ? 0.0f : dec(gk.y);
                o.z = (gk.z == EPSK) ? 0.0f : dec(gk.z);
                o.w = (gk.w == EPSK) ? 0.0f : dec(gk.w);
                o4[864 + idx] = o;
            }
        }
    }
}

extern "C" void kernel_launch(void* const* d_in, const int* in_sizes, int n_in,
                              void* d_out, int out_size, void* d_ws, size_t ws_size,
                              hipStream_t stream) {
    const float* img = (const float*)d_in[0];    // (64,64,64,64)
    const float* depth = (const float*)d_in[1];  // (64,3,256,256)
    float* out = (float*)d_out;                  // (64,64,128,128)

    mapnet_pipe<<<256, 1024, 0, stream>>>(img, depth, out);
}